// Round 8
// baseline (167.203 us; speedup 1.0000x reference)
//
#include <hip/hip_runtime.h>
#include <math.h>

// Problem constants
#define H_GRID 32
#define W_GRID 64
#define NTOK   2048
#define NHEADS 8
#define HD     24
#define DIMC   192
#define BATCH  4

static constexpr float SCALE = 0.20412414523193154f; // 1/sqrt(24)

typedef unsigned short ushort;
typedef unsigned int   uint;
typedef __attribute__((ext_vector_type(8))) short bf16x8;
typedef __attribute__((ext_vector_type(4))) float f32x4;

static __device__ __forceinline__ float4 ld4(const float* p) { return *(const float4*)p; }

static __device__ __forceinline__ ushort f2bf(float f) {   // RNE to bf16
    union { float f; uint u; } c; c.f = f;
    uint u = c.u;
    uint r = u + 0x7fffu + ((u >> 16) & 1u);
    return (ushort)(r >> 16);
}
static __device__ __forceinline__ float bf2f(ushort h) {
    union { uint u; float f; } c; c.u = ((uint)h) << 16; return c.f;
}

// ---------------------------------------------------------------------------
// cast_split: split x, qkv_w, proj_w into bf16 hi/lo; zero-fill Q/K d-pads.
// ---------------------------------------------------------------------------
__global__ __launch_bounds__(256) void cast_split(const float* __restrict__ x,
                                                  const float* __restrict__ wq,
                                                  const float* __restrict__ wp,
                                                  ushort* __restrict__ xhi, ushort* __restrict__ xlo,
                                                  ushort* __restrict__ wqhi, ushort* __restrict__ wqlo,
                                                  ushort* __restrict__ wphi, ushort* __restrict__ wplo,
                                                  ushort* __restrict__ Qhi, ushort* __restrict__ Qlo,
                                                  ushort* __restrict__ Khi, ushort* __restrict__ Klo) {
    const int i = blockIdx.x * 256 + threadIdx.x;
    if (i >= 430080) {                       // zero-fill Q/K pads (d=24..31)
        const int ti = i - 430080;           // 0..262143
        const int tensor = ti >> 16;
        const int row = ti & 65535;
        ushort* dst = (tensor == 0) ? Qhi : (tensor == 1) ? Qlo
                    : (tensor == 2) ? Khi : Klo;
        const uint4 z = {0u, 0u, 0u, 0u};
        *(uint4*)&dst[(size_t)row * 32 + 24] = z;
        return;
    }
    const float* src; ushort *dh, *dl; int off;
    if (i < 393216)      { src = x;  dh = xhi;  dl = xlo;  off = i; }
    else if (i < 420864) { src = wq; dh = wqhi; dl = wqlo; off = i - 393216; }
    else                 { src = wp; dh = wphi; dl = wplo; off = i - 420864; }
    float4 v = ld4(src + (size_t)off * 4);
    float a[4] = {v.x, v.y, v.z, v.w};
    ushort h[4], l[4];
#pragma unroll
    for (int j = 0; j < 4; j++) {
        h[j] = f2bf(a[j]);
        l[j] = f2bf(a[j] - bf2f(h[j]));
    }
    *(ushort4*)(dh + (size_t)off * 4) = make_ushort4(h[0], h[1], h[2], h[3]);
    *(ushort4*)(dl + (size_t)off * 4) = make_ushort4(l[0], l[1], l[2], l[3]);
}

// ---------------------------------------------------------------------------
// QKV GEMM (split-bf16 MFMA) -> attention-ready layouts:
//   Q/K: [bh][tok][32] (d-pad zeros), q scaled; V: VT [bh][d(32)][2064] with
//   token offset +8 (guard for window underflow; keeps b128 reads aligned).
// W band in LDS (rows padded to 200 us = 2-way/free).
// ---------------------------------------------------------------------------
__global__ __launch_bounds__(256) void gemm_qkv(const ushort* __restrict__ Ahi,
                                                const ushort* __restrict__ Alo,
                                                const ushort* __restrict__ Wh,
                                                const ushort* __restrict__ Wl,
                                                const float* __restrict__ bias,
                                                ushort* __restrict__ Qhi, ushort* __restrict__ Qlo,
                                                ushort* __restrict__ Khi, ushort* __restrict__ Klo,
                                                ushort* __restrict__ VThi, ushort* __restrict__ VTlo) {
    __shared__ ushort Wsh[64 * 200];
    __shared__ ushort Wsl[64 * 200];

    const int t    = threadIdx.x;
    const int wave = t >> 6, lane = t & 63;
    const int m0   = blockIdx.x * 64 + wave * 16;
    const int j0   = blockIdx.y * 64;
    const int row  = lane & 15;
    const int kq   = lane >> 4;

    for (int i = t; i < 1536; i += 256) {
        const int r = i / 24, c = i - (i / 24) * 24;
        *(uint4*)&Wsh[r * 200 + c * 8] = *(const uint4*)&Wh[(size_t)(j0 + r) * 192 + c * 8];
        *(uint4*)&Wsl[r * 200 + c * 8] = *(const uint4*)&Wl[(size_t)(j0 + r) * 192 + c * 8];
    }

    const ushort* ah = Ahi + (size_t)(m0 + row) * 192 + kq * 8;
    const ushort* al = Alo + (size_t)(m0 + row) * 192 + kq * 8;

    f32x4 acc[4] = {f32x4{0,0,0,0}, f32x4{0,0,0,0}, f32x4{0,0,0,0}, f32x4{0,0,0,0}};

    __syncthreads();

#pragma unroll
    for (int ks = 0; ks < 6; ks++) {
        bf16x8 afh = *(const bf16x8*)(ah + ks * 32);
        bf16x8 afl = *(const bf16x8*)(al + ks * 32);
#pragma unroll
        for (int nt = 0; nt < 4; nt++) {
            const int widx = (nt * 16 + row) * 200 + kq * 8 + ks * 32;
            bf16x8 bh = *(const bf16x8*)&Wsh[widx];
            bf16x8 bl = *(const bf16x8*)&Wsl[widx];
            acc[nt] = __builtin_amdgcn_mfma_f32_16x16x32_bf16(afh, bh, acc[nt], 0, 0, 0);
            acc[nt] = __builtin_amdgcn_mfma_f32_16x16x32_bf16(afl, bh, acc[nt], 0, 0, 0);
            acc[nt] = __builtin_amdgcn_mfma_f32_16x16x32_bf16(afh, bl, acc[nt], 0, 0, 0);
        }
    }

    const int band = blockIdx.y / 3;          // 0=Q, 1=K, 2=V
    const int tok0 = (m0 + kq * 4) & 2047;
    const int b_   = (m0 + kq * 4) >> 11;
#pragma unroll
    for (int nt = 0; nt < 4; nt++) {
        const int col = j0 + nt * 16 + row;
        const int lc  = col - band * 192;
        const int h_  = lc / 24;
        const int d_  = lc - h_ * 24;
        const float bv = bias[col];
        if (band == 2) {                      // V -> VT[bh][d][2064]+8
            ushort vh[4], vl[4];
#pragma unroll
            for (int r = 0; r < 4; r++) {
                const float val = acc[nt][r] + bv;
                vh[r] = f2bf(val);
                vl[r] = f2bf(val - bf2f(vh[r]));
            }
            const size_t addr = ((size_t)(b_ * 8 + h_) * 32 + d_) * 2064 + 8 + tok0;
            *(ushort4*)&VThi[addr] = make_ushort4(vh[0], vh[1], vh[2], vh[3]);
            *(ushort4*)&VTlo[addr] = make_ushort4(vl[0], vl[1], vl[2], vl[3]);
        } else {
            ushort* dh = band ? Khi : Qhi;
            ushort* dl = band ? Klo : Qlo;
            const float sc_ = band ? 1.0f : SCALE;
#pragma unroll
            for (int r = 0; r < 4; r++) {
                const float val = (acc[nt][r] + bv) * sc_;
                const ushort hh = f2bf(val);
                const size_t addr = ((size_t)(b_ * 8 + h_) * 2048 + tok0 + r) * 32 + d_;
                dh[addr] = hh;
                dl[addr] = f2bf(val - bf2f(hh));
            }
        }
    }
}

// ---------------------------------------------------------------------------
// Fused attention + projection. One block (512 thr, 8 waves) per
// (b, qh, 32-token strip). Per head: QK^T (2 m-tiles x 21 n-tiles over a
// 7x48 slot window, direct-global split-bf16 frags), softmax (shuffle +
// 4-way wave LDS combine), P->LDS bf16, PV (waves 0-3, V^T direct global),
// O -> LDS bf16 hi/lo. After 8 heads: proj GEMM from LDS O, W direct global.
// No aws round-trip, no 2B global scatter. LDS ~49.6 KB.
// ---------------------------------------------------------------------------
__global__ __launch_bounds__(512) void attn_proj(const ushort* __restrict__ Qhi,
                                                 const ushort* __restrict__ Qlo,
                                                 const ushort* __restrict__ Khi,
                                                 const ushort* __restrict__ Klo,
                                                 const ushort* __restrict__ VThi,
                                                 const ushort* __restrict__ VTlo,
                                                 const ushort* __restrict__ Wph,
                                                 const ushort* __restrict__ Wpl,
                                                 const float* __restrict__ proj_b,
                                                 float* __restrict__ out) {
    const int bx  = blockIdx.x;          // 0..255
    const int b   = bx >> 6;
    const int qh  = (bx >> 1) & 31;
    const int qws = bx & 1;
    const int qw0 = qws * 32;

    const int t = threadIdx.x;
    const int w = t >> 6, lane = t & 63;
    const int n16 = lane & 15, quad = lane >> 4;

    __shared__ ushort Phi[32 * 360];     // P (bf16 hi), cols 0..335 + zero pad
    __shared__ ushort Ohi[32 * 200];     // attn out hi (rows padded: 100w==4 mod 32)
    __shared__ ushort Olo[32 * 200];
    __shared__ float  mxbuf[8 * 16];
    __shared__ float  sumbuf[8 * 16];

    // zero the P pad cols [336,360) once (read by PV kstep 10)
    if (t < 96) {
        const int prow = t / 3, ch = t - (t / 3) * 3;
        const uint4 z = {0u, 0u, 0u, 0u};
        *(uint4*)&Phi[prow * 360 + 336 + ch * 8] = z;
    }

    const int mt   = w >> 2;             // QK m-tile (0..1)
    const int nth  = w & 3;              // QK n-group (0..3)
    const int mrow = 16 * mt + n16;
    const int tq_a = (qh << 6) + qw0 + mrow;
    const int njt  = (nth == 0) ? 6 : 5; // tiles jj = nth + 4j < 21

    for (int head = 0; head < 8; head++) {
        const int bh = b * 8 + head;
        const ushort* Qh_b = Qhi + (size_t)bh * 65536;
        const ushort* Ql_b = Qlo + (size_t)bh * 65536;
        const ushort* Kh_b = Khi + (size_t)bh * 65536;
        const ushort* Kl_b = Klo + (size_t)bh * 65536;

        const bf16x8 qfh = *(const bf16x8*)&Qh_b[(size_t)tq_a * 32 + quad * 8];
        const bf16x8 qfl = *(const bf16x8*)&Ql_b[(size_t)tq_a * 32 + quad * 8];

        float sv[6][4];
        float mx4[4] = {-3e38f, -3e38f, -3e38f, -3e38f};
        for (int j = 0; j < njt; j++) {
            const int jj   = nth + 4 * j;
            const int slot = jj * 16 + n16;
            const int rr   = slot / 48;
            const int cc   = slot - rr * 48;
            const int khv  = qh - 3 + rr;
            const int kwv  = qw0 - 8 + cc;
            const int kh_cl = min(max(khv, 0), 31);
            const int kw_cl = min(max(kwv, 0), 63);
            const int tok   = (kh_cl << 6) + kw_cl;
            const bf16x8 kfh = *(const bf16x8*)&Kh_b[(size_t)tok * 32 + quad * 8];
            const bf16x8 kfl = *(const bf16x8*)&Kl_b[(size_t)tok * 32 + quad * 8];
            f32x4 a = f32x4{0, 0, 0, 0};
            a = __builtin_amdgcn_mfma_f32_16x16x32_bf16(qfh, kfh, a, 0, 0, 0);
            a = __builtin_amdgcn_mfma_f32_16x16x32_bf16(qfl, kfh, a, 0, 0, 0);
            a = __builtin_amdgcn_mfma_f32_16x16x32_bf16(qfh, kfl, a, 0, 0, 0);
            const bool kok = (khv >= 0) && (khv < 32) && (kwv >= 0) && (kwv < 64);
#pragma unroll
            for (int r = 0; r < 4; r++) {
                const int m = 16 * mt + quad * 4 + r;
                const bool valid = kok && (abs(kwv - (qw0 + m)) <= 5);
                const float s = valid ? a[r] : -3e38f;
                sv[j][r] = s;
                mx4[r] = fmaxf(mx4[r], s);
            }
        }
#pragma unroll
        for (int d = 1; d < 16; d <<= 1)
#pragma unroll
            for (int r = 0; r < 4; r++) mx4[r] = fmaxf(mx4[r], __shfl_xor(mx4[r], d));
        if (n16 == 0) {
#pragma unroll
            for (int r = 0; r < 4; r++) mxbuf[w * 16 + quad * 4 + r] = mx4[r];
        }
        __syncthreads();   // sync_a: mxbuf ready; prior head's PV complete
#pragma unroll
        for (int r = 0; r < 4; r++) {
            float m_ = mxbuf[(mt * 4 + 0) * 16 + quad * 4 + r];
            m_ = fmaxf(m_, mxbuf[(mt * 4 + 1) * 16 + quad * 4 + r]);
            m_ = fmaxf(m_, mxbuf[(mt * 4 + 2) * 16 + quad * 4 + r]);
            m_ = fmaxf(m_, mxbuf[(mt * 4 + 3) * 16 + quad * 4 + r]);
            mx4[r] = m_;
        }

        float sum4[4] = {0.f, 0.f, 0.f, 0.f};
        for (int j = 0; j < njt; j++) {
            const int col = (nth + 4 * j) * 16 + n16;
#pragma unroll
            for (int r = 0; r < 4; r++) {
                const float p = __expf(sv[j][r] - mx4[r]);
                const ushort ph = f2bf(p);
                sum4[r] += bf2f(ph);
                Phi[(16 * mt + quad * 4 + r) * 360 + col] = ph;
            }
        }
#pragma unroll
        for (int d = 1; d < 16; d <<= 1)
#pragma unroll
            for (int r = 0; r < 4; r++) sum4[r] += __shfl_xor(sum4[r], d);
        if (n16 == 0) {
#pragma unroll
            for (int r = 0; r < 4; r++) sumbuf[w * 16 + quad * 4 + r] = sum4[r];
        }
        __syncthreads();   // sync_b: P + sumbuf ready

        if (w < 4) {       // PV on waves 0..3
            const int mtP = w >> 1, ntP = w & 1;
            const int dcol = 16 * ntP + n16;
            const ushort* Vh_b = VThi + (size_t)bh * 66048;   // 32*2064
            const ushort* Vl_b = VTlo + (size_t)bh * 66048;
            f32x4 accA = f32x4{0,0,0,0}, accB = f32x4{0,0,0,0};
#pragma unroll
            for (int ks = 0; ks < 11; ks++) {
                const int s0  = ks * 32 + quad * 8;
                const int rr  = s0 / 48;
                const int cc0 = s0 - rr * 48;
                const int kh_cl = min(max(qh - 3 + rr, 0), 31);
                const int tok0  = (kh_cl << 6) + qw0 - 8 + cc0;
                const bf16x8 pa = *(const bf16x8*)&Phi[(16 * mtP + n16) * 360 + s0];
                const bf16x8 vh = *(const bf16x8*)&Vh_b[(size_t)dcol * 2064 + 8 + tok0];
                const bf16x8 vl = *(const bf16x8*)&Vl_b[(size_t)dcol * 2064 + 8 + tok0];
                accA = __builtin_amdgcn_mfma_f32_16x16x32_bf16(pa, vh, accA, 0, 0, 0);
                accB = __builtin_amdgcn_mfma_f32_16x16x32_bf16(pa, vl, accB, 0, 0, 0);
            }
            if (dcol < 24) {
#pragma unroll
                for (int r = 0; r < 4; r++) {
                    const int m = 16 * mtP + quad * 4 + r;
                    float tot = sumbuf[(mtP * 4 + 0) * 16 + (m & 15)]
                              + sumbuf[(mtP * 4 + 1) * 16 + (m & 15)]
                              + sumbuf[(mtP * 4 + 2) * 16 + (m & 15)]
                              + sumbuf[(mtP * 4 + 3) * 16 + (m & 15)];
                    const float val = (accA[r] + accB[r]) / tot;
                    const ushort hh = f2bf(val);
                    Ohi[m * 200 + head * 24 + dcol] = hh;
                    Olo[m * 200 + head * 24 + dcol] = f2bf(val - bf2f(hh));
                }
            }
        }
    }
    __syncthreads();       // O complete

    // ---- projection: rows = this strip's 32 tokens, cols 192 ----
    const int mtj = w >> 2;              // 0..1
    const int nh  = w & 3;               // cols nh*48..+47 (3 n-tiles)
    bf16x8 afh[6], afl[6];
#pragma unroll
    for (int ks = 0; ks < 6; ks++) {
        afh[ks] = *(const bf16x8*)&Ohi[(16 * mtj + n16) * 200 + ks * 32 + quad * 8];
        afl[ks] = *(const bf16x8*)&Olo[(16 * mtj + n16) * 200 + ks * 32 + quad * 8];
    }
    f32x4 acc[3] = {f32x4{0,0,0,0}, f32x4{0,0,0,0}, f32x4{0,0,0,0}};
#pragma unroll
    for (int nt = 0; nt < 3; nt++) {
        const int col0 = nh * 48 + nt * 16;
#pragma unroll
        for (int ks = 0; ks < 6; ks++) {
            const size_t boff = (size_t)(col0 + n16) * 192 + ks * 32 + quad * 8;
            const bf16x8 bh8 = *(const bf16x8*)&Wph[boff];
            const bf16x8 bl8 = *(const bf16x8*)&Wpl[boff];
            acc[nt] = __builtin_amdgcn_mfma_f32_16x16x32_bf16(afh[ks], bh8, acc[nt], 0, 0, 0);
            acc[nt] = __builtin_amdgcn_mfma_f32_16x16x32_bf16(afl[ks], bh8, acc[nt], 0, 0, 0);
            acc[nt] = __builtin_amdgcn_mfma_f32_16x16x32_bf16(afh[ks], bl8, acc[nt], 0, 0, 0);
        }
    }
    const int rowbase = b * 2048 + (qh << 6) + qw0;
#pragma unroll
    for (int nt = 0; nt < 3; nt++) {
        const int col = nh * 48 + nt * 16 + n16;
        const float bv = proj_b[col];
#pragma unroll
        for (int r = 0; r < 4; r++) {
            const int m = 16 * mtj + quad * 4 + r;
            out[(size_t)(rowbase + m) * 192 + col] = acc[nt][r] + bv;
        }
    }
}

// ---------------------------------------------------------------------------
// Launch: cast_split -> gemm_qkv -> attn_proj
// ---------------------------------------------------------------------------
extern "C" void kernel_launch(void* const* d_in, const int* in_sizes, int n_in,
                              void* d_out, int out_size, void* d_ws, size_t ws_size,
                              hipStream_t stream) {
    const float* x      = (const float*)d_in[0];
    const float* qkv_w  = (const float*)d_in[1];
    const float* qkv_b  = (const float*)d_in[2];
    const float* proj_w = (const float*)d_in[3];
    const float* proj_b = (const float*)d_in[4];
    // d_in[5] mask: fixed 7x11 window, recomputed analytically; unused.

    char* wsb = (char*)d_ws;
    ushort* xhi   = (ushort*)(wsb + 0);          // [8192,192]
    ushort* xlo   = (ushort*)(wsb + 3145728);
    ushort* wqhi  = (ushort*)(wsb + 6291456);    // [576,192]
    ushort* wqlo  = (ushort*)(wsb + 6512640);
    ushort* wphi  = (ushort*)(wsb + 6733824);    // [192,192]
    ushort* wplo  = (ushort*)(wsb + 6807552);
    ushort* Qhi   = (ushort*)(wsb + 6881280);    // [32,2048,32]
    ushort* Qlo   = (ushort*)(wsb + 11075584);
    ushort* Khi   = (ushort*)(wsb + 15269888);
    ushort* Klo   = (ushort*)(wsb + 19464192);
    ushort* VThi  = (ushort*)(wsb + 23658496);   // [32,32,2064]
    ushort* VTlo  = (ushort*)(wsb + 27885568);
    float*  out   = (float*)d_out;

    hipLaunchKernelGGL(cast_split, dim3(2704), dim3(256), 0, stream,
                       x, qkv_w, proj_w, xhi, xlo, wqhi, wqlo, wphi, wplo,
                       Qhi, Qlo, Khi, Klo);
    hipLaunchKernelGGL(gemm_qkv, dim3(128, 9), dim3(256), 0, stream,
                       xhi, xlo, wqhi, wqlo, qkv_b,
                       Qhi, Qlo, Khi, Klo, VThi, VTlo);
    hipLaunchKernelGGL(attn_proj, dim3(256), dim3(512), 0, stream,
                       Qhi, Qlo, Khi, Klo, VThi, VTlo,
                       wphi, wplo, proj_b, out);
}

// Round 9
// 115.241 us; speedup vs baseline: 1.4509x; 1.4509x over previous
//
#include <hip/hip_runtime.h>
#include <math.h>

// Problem constants
#define H_GRID 32
#define W_GRID 64
#define NTOK   2048
#define NHEADS 8
#define HD     24
#define DIMC   192
#define BATCH  4

static constexpr float SCALE = 0.20412414523193154f; // 1/sqrt(24)

typedef unsigned short ushort;
typedef unsigned int   uint;
typedef __attribute__((ext_vector_type(8))) _Float16 f16x8;
typedef __attribute__((ext_vector_type(4))) float    f32x4;

static __device__ __forceinline__ float4 ld4(const float* p) { return *(const float4*)p; }

static __device__ __forceinline__ ushort f2h(float f) {
    _Float16 h = (_Float16)f;
    union { _Float16 h; ushort u; } c; c.h = h; return c.u;
}
static __device__ __forceinline__ float h2f(ushort u) {
    union { ushort u; _Float16 h; } c; c.u = u; return (float)c.h;
}

// ---------------------------------------------------------------------------
// cast_h: convert x, qkv_w, proj_w to fp16; zero-fill Q/K d-pads (24..31).
// Ranges: [0,393216) x chunks; [393216,420864) wq; [420864,430080) wp;
//         [430080,561152) zero-fills (2 tensors x 65536 rows, 16B each).
// ---------------------------------------------------------------------------
__global__ __launch_bounds__(256) void cast_h(const float* __restrict__ x,
                                              const float* __restrict__ wq,
                                              const float* __restrict__ wp,
                                              ushort* __restrict__ xh,
                                              ushort* __restrict__ wqh,
                                              ushort* __restrict__ wph,
                                              ushort* __restrict__ Qh,
                                              ushort* __restrict__ Kh) {
    const int i = blockIdx.x * 256 + threadIdx.x;
    if (i >= 430080) {
        const int ti = i - 430080;            // 0..131071
        ushort* dst = (ti >> 16) ? Kh : Qh;
        const int row = ti & 65535;
        const uint4 z = {0u, 0u, 0u, 0u};
        *(uint4*)&dst[(size_t)row * 32 + 24] = z;
        return;
    }
    const float* src; ushort* dh; int off;
    if (i < 393216)      { src = x;  dh = xh;  off = i; }
    else if (i < 420864) { src = wq; dh = wqh; off = i - 393216; }
    else                 { src = wp; dh = wph; off = i - 420864; }
    float4 v = ld4(src + (size_t)off * 4);
    *(ushort4*)(dh + (size_t)off * 4) =
        make_ushort4(f2h(v.x), f2h(v.y), f2h(v.z), f2h(v.w));
}

// ---------------------------------------------------------------------------
// QKV GEMM (fp16 MFMA): C = x @ W^T + bias -> attention-ready layouts:
//   Q/K: [bh][tok][32] fp16 (d-pads pre-zeroed), q scaled by 1/sqrt(24)
//   V:   VT [bh][d(32 rows, 24 used)][2080] fp16, token offset +8 (guards)
// W band (64x192 fp16) in LDS rows padded to 200 (2-way = free).
// Q/K epilogue: LDS transpose (reusing W buffer) -> coalesced ushort4 stores.
// ---------------------------------------------------------------------------
__global__ __launch_bounds__(256) void gemm_qkv(const ushort* __restrict__ Ah,
                                                const ushort* __restrict__ Wh,
                                                const float* __restrict__ bias,
                                                ushort* __restrict__ Qh,
                                                ushort* __restrict__ Kh,
                                                ushort* __restrict__ VTh) {
    __shared__ ushort Ws[64 * 200];   // W stage; reused as 64x68 transpose buf

    const int t    = threadIdx.x;
    const int wave = t >> 6, lane = t & 63;
    const int m0   = blockIdx.x * 64 + wave * 16;
    const int j0   = blockIdx.y * 64;
    const int n16  = lane & 15;
    const int kq   = lane >> 4;

    for (int i = t; i < 1536; i += 256) {
        const int r = i / 24, c = i - (i / 24) * 24;
        *(uint4*)&Ws[r * 200 + c * 8] = *(const uint4*)&Wh[(size_t)(j0 + r) * 192 + c * 8];
    }

    const ushort* ap = Ah + (size_t)(m0 + n16) * 192 + kq * 8;

    f32x4 acc[4] = {f32x4{0,0,0,0}, f32x4{0,0,0,0}, f32x4{0,0,0,0}, f32x4{0,0,0,0}};

    __syncthreads();

#pragma unroll
    for (int ks = 0; ks < 6; ks++) {
        const f16x8 af = *(const f16x8*)(ap + ks * 32);
#pragma unroll
        for (int nt = 0; nt < 4; nt++) {
            const f16x8 bf = *(const f16x8*)&Ws[(nt * 16 + n16) * 200 + kq * 8 + ks * 32];
            acc[nt] = __builtin_amdgcn_mfma_f32_16x16x32_f16(af, bf, acc[nt], 0, 0, 0);
        }
    }

    // C layout: col = n16 (+16nt), row(token) = kq*4 + r
    const int band = blockIdx.y / 3;          // 0=Q, 1=K, 2=V
    const int mrow0 = m0 + kq * 4;
    const int b_    = mrow0 >> 11;
    const int tok0  = mrow0 & 2047;

    if (band == 2) {                          // V -> VT[bh][d][2080]+8, direct
#pragma unroll
        for (int nt = 0; nt < 4; nt++) {
            const int col = j0 + nt * 16 + n16;
            const int lc  = col - 384;
            const int h_  = lc / 24;
            const int d_  = lc - h_ * 24;
            const float bv = bias[col];
            ushort vv[4];
#pragma unroll
            for (int r = 0; r < 4; r++) vv[r] = f2h(acc[nt][r] + bv);
            const size_t addr = ((size_t)(b_ * 8 + h_) * 32 + d_) * 2080 + 8 + tok0;
            *(ushort4*)&VTh[addr] = make_ushort4(vv[0], vv[1], vv[2], vv[3]);
        }
    } else {                                  // Q/K -> LDS transpose -> coalesced
        const float sc_ = band ? 1.0f : SCALE;
        __syncthreads();                      // W reads done; reuse Ws
#pragma unroll
        for (int nt = 0; nt < 4; nt++) {
            const int col = j0 + nt * 16 + n16;
            const float bv = bias[col];
#pragma unroll
            for (int r = 0; r < 4; r++) {
                Ws[(wave * 16 + kq * 4 + r) * 68 + nt * 16 + n16] =
                    f2h((acc[nt][r] + bv) * sc_);
            }
        }
        __syncthreads();
        ushort* dst = band ? Kh : Qh;
        const int lc0 = j0 - band * 192;      // 0, 64, or 128
#pragma unroll
        for (int it = 0; it < 4; it++) {
            const int item = t + 256 * it;    // 0..1023
            const int tokl = item >> 4;
            const int cg   = item & 15;
            const ushort4 v = *(const ushort4*)&Ws[tokl * 68 + cg * 4];
            const int lc = lc0 + cg * 4;
            const int h_ = lc / 24;
            const int d0 = lc - h_ * 24;
            const int m  = blockIdx.x * 64 + tokl;
            const size_t addr = ((size_t)((m >> 11) * 8 + h_) * 2048 + (m & 2047)) * 32 + d0;
            *(ushort4*)&dst[addr] = v;
        }
    }
}

// ---------------------------------------------------------------------------
// MFMA local attention (fp16). One block (4 waves) per (b, head, 4x8 q-tile).
// Window: kh = qh0-3..qh0+6 (10 rows) x kw = [qw0-8, qw0+24) (32 cols)
//   -> 320 slots, slot = rr*32+cc. OOB slots clamped (finite) + masked.
// QK^T: Q/K frags direct from global; 10 n-tiles/wave, 1 MFMA each.
// Softmax: shuffle over 16 lanes + partner-wave LDS combine; P fp16 in LDS.
// PV: P A-frags from LDS, V^T B-frags direct global; 10 ksteps (= kh rows).
// Output: LDS transpose -> coalesced ushort4 stores to aws fp16 [8192][192].
// LDS ~23 KB -> ~6 blocks/CU.
// ---------------------------------------------------------------------------
__global__ __launch_bounds__(256) void attn_mfma(const ushort* __restrict__ Qh,
                                                 const ushort* __restrict__ Kh,
                                                 const ushort* __restrict__ VTh,
                                                 ushort* __restrict__ aws) {
    const int qtile = blockIdx.x;
    const int head  = blockIdx.y;
    const int b     = blockIdx.z;
    const int qh0   = (qtile >> 3) * 4;
    const int qw0   = (qtile & 7) * 8;
    const int kw0a  = qw0 - 8;                // may be negative (clamped+masked)

    const int t = threadIdx.x;
    const int w = t >> 6, lane = t & 63;
    const int n16 = lane & 15, quad = lane >> 4;
    const int bh = b * 8 + head;

    __shared__ ushort P[32 * 328];            // stride 328: 164w %32 = 4 (free)
    __shared__ ushort Os[32 * 28];
    __shared__ float  mxbuf[64], sumbuf[64];

    const ushort* Qb = Qh + (size_t)bh * 65536;
    const ushort* Kb = Kh + (size_t)bh * 65536;

    const int mt = w >> 1, nth = w & 1;
    const int mrow = 16 * mt + n16;
    const int tq_a = ((qh0 + (mrow >> 3)) << 6) + qw0 + (mrow & 7);
    const f16x8 qf = *(const f16x8*)&Qb[(size_t)tq_a * 32 + quad * 8];

    float sv[10][4];
    float mx4[4] = {-3e38f, -3e38f, -3e38f, -3e38f};
#pragma unroll
    for (int j = 0; j < 10; j++) {
        const int slot = (nth * 10 + j) * 16 + n16;
        const int rr = slot >> 5, cc = slot & 31;
        const int khv = qh0 - 3 + rr;
        const int kwv = kw0a + cc;
        const int tok = (min(max(khv, 0), 31) << 6) + min(max(kwv, 0), 63);
        const f16x8 kf = *(const f16x8*)&Kb[(size_t)tok * 32 + quad * 8];
        f32x4 a = f32x4{0, 0, 0, 0};
        a = __builtin_amdgcn_mfma_f32_16x16x32_f16(qf, kf, a, 0, 0, 0);
        const bool kok = (khv >= 0) && (khv < 32) && (kwv >= 0) && (kwv < 64);
#pragma unroll
        for (int r = 0; r < 4; r++) {
            const int m   = 16 * mt + quad * 4 + r;
            const int qhv = qh0 + (m >> 3);
            const int qwv = qw0 + (m & 7);
            const bool valid = kok && (abs(khv - qhv) <= 3) && (abs(kwv - qwv) <= 5);
            const float s = valid ? a[r] : -3e38f;
            sv[j][r] = s;
            mx4[r] = fmaxf(mx4[r], s);
        }
    }
#pragma unroll
    for (int d = 1; d < 16; d <<= 1)
#pragma unroll
        for (int r = 0; r < 4; r++) mx4[r] = fmaxf(mx4[r], __shfl_xor(mx4[r], d));
    if (n16 == 0) {
#pragma unroll
        for (int r = 0; r < 4; r++) mxbuf[w * 16 + quad * 4 + r] = mx4[r];
    }
    __syncthreads();
#pragma unroll
    for (int r = 0; r < 4; r++) mx4[r] = fmaxf(mx4[r], mxbuf[(w ^ 1) * 16 + quad * 4 + r]);

    float sum4[4] = {0.f, 0.f, 0.f, 0.f};
#pragma unroll
    for (int j = 0; j < 10; j++) {
        const int slot = (nth * 10 + j) * 16 + n16;
#pragma unroll
        for (int r = 0; r < 4; r++) {
            const float p = __expf(sv[j][r] - mx4[r]);
            const ushort ph = f2h(p);
            sum4[r] += h2f(ph);
            P[(16 * mt + quad * 4 + r) * 328 + slot] = ph;
        }
    }
#pragma unroll
    for (int d = 1; d < 16; d <<= 1)
#pragma unroll
        for (int r = 0; r < 4; r++) sum4[r] += __shfl_xor(sum4[r], d);
    if (n16 == 0) {
#pragma unroll
        for (int r = 0; r < 4; r++) sumbuf[w * 16 + quad * 4 + r] = sum4[r];
    }
    __syncthreads();

    // ---- PV ----
    const int mtP = w >> 1, ntP = w & 1;
    const int dcol = 16 * ntP + n16;
    const ushort* VTb = VTh + (size_t)bh * 32 * 2080;
    f32x4 acc = f32x4{0, 0, 0, 0};
#pragma unroll
    for (int ks = 0; ks < 10; ks++) {
        const int kh_cl = min(max(qh0 - 3 + ks, 0), 31);
        const f16x8 pa = *(const f16x8*)&P[(16 * mtP + n16) * 328 + ks * 32 + quad * 8];
        const f16x8 vf = *(const f16x8*)&VTb[(size_t)dcol * 2080 + 8 + (kh_cl << 6) + kw0a + quad * 8];
        acc = __builtin_amdgcn_mfma_f32_16x16x32_f16(pa, vf, acc, 0, 0, 0);
    }
    if (dcol < 24) {
#pragma unroll
        for (int r = 0; r < 4; r++) {
            const int m = 16 * mtP + quad * 4 + r;
            const float tot = sumbuf[(2 * mtP) * 16 + (m & 15)] +
                              sumbuf[(2 * mtP + 1) * 16 + (m & 15)];
            Os[m * 28 + dcol] = f2h(acc[r] / tot);
        }
    }
    __syncthreads();

    // ---- coalesced output: 32 tokens x 24 dims ----
    if (t < 192) {
        const int tok = t / 6, g = t - (t / 6) * 6;
        const ushort4 v = *(const ushort4*)&Os[tok * 28 + g * 4];
        const int tq = ((qh0 + (tok >> 3)) << 6) + qw0 + (tok & 7);
        *(ushort4*)&aws[((size_t)(b * 2048 + tq)) * 192 + head * 24 + g * 4] = v;
    }
}

// ---------------------------------------------------------------------------
// Proj GEMM (fp16 MFMA): out[8192x192] = aws @ Wp^T + bias (fp32 out).
// 128-thread blocks, 32 rows each -> 768 blocks. W band in LDS (stride 200).
// ---------------------------------------------------------------------------
__global__ __launch_bounds__(128) void gemm_proj(const ushort* __restrict__ Ah,
                                                 const ushort* __restrict__ Wh,
                                                 const float* __restrict__ bias,
                                                 float* __restrict__ C) {
    __shared__ ushort Ws[64 * 200];

    const int t    = threadIdx.x;
    const int wave = t >> 6, lane = t & 63;
    const int m0   = blockIdx.x * 32 + wave * 16;
    const int j0   = blockIdx.y * 64;
    const int n16  = lane & 15;
    const int kq   = lane >> 4;

    for (int i = t; i < 1536; i += 128) {
        const int r = i / 24, c = i - (i / 24) * 24;
        *(uint4*)&Ws[r * 200 + c * 8] = *(const uint4*)&Wh[(size_t)(j0 + r) * 192 + c * 8];
    }

    const ushort* ap = Ah + (size_t)(m0 + n16) * 192 + kq * 8;

    f32x4 acc[4] = {f32x4{0,0,0,0}, f32x4{0,0,0,0}, f32x4{0,0,0,0}, f32x4{0,0,0,0}};

    __syncthreads();

#pragma unroll
    for (int ks = 0; ks < 6; ks++) {
        const f16x8 af = *(const f16x8*)(ap + ks * 32);
#pragma unroll
        for (int nt = 0; nt < 4; nt++) {
            const f16x8 bf = *(const f16x8*)&Ws[(nt * 16 + n16) * 200 + kq * 8 + ks * 32];
            acc[nt] = __builtin_amdgcn_mfma_f32_16x16x32_f16(af, bf, acc[nt], 0, 0, 0);
        }
    }

#pragma unroll
    for (int nt = 0; nt < 4; nt++) {
        const int col = j0 + nt * 16 + n16;
        const float bv = bias[col];
#pragma unroll
        for (int r = 0; r < 4; r++) {
            const int m = m0 + kq * 4 + r;
            C[(size_t)m * 192 + col] = acc[nt][r] + bv;
        }
    }
}

// ---------------------------------------------------------------------------
// Launch: cast_h -> gemm_qkv -> attn_mfma -> gemm_proj
// ---------------------------------------------------------------------------
extern "C" void kernel_launch(void* const* d_in, const int* in_sizes, int n_in,
                              void* d_out, int out_size, void* d_ws, size_t ws_size,
                              hipStream_t stream) {
    const float* x      = (const float*)d_in[0];
    const float* qkv_w  = (const float*)d_in[1];
    const float* qkv_b  = (const float*)d_in[2];
    const float* proj_w = (const float*)d_in[3];
    const float* proj_b = (const float*)d_in[4];
    // d_in[5] mask: fixed 7x11 window, recomputed analytically; unused.

    char* wsb = (char*)d_ws;
    ushort* xh   = (ushort*)(wsb + 0);          // [8192,192] fp16
    ushort* wqh  = (ushort*)(wsb + 3145728);    // [576,192]
    ushort* wph  = (ushort*)(wsb + 3366912);    // [192,192]
    ushort* Qh   = (ushort*)(wsb + 3440640);    // [32,2048,32]
    ushort* Kh   = (ushort*)(wsb + 7634944);    // [32,2048,32]
    ushort* VTh  = (ushort*)(wsb + 11829248);   // [32,32,2080]
    ushort* awsh = (ushort*)(wsb + 16171008);   // [8192,192]
    float*  out  = (float*)d_out;

    hipLaunchKernelGGL(cast_h, dim3(2192), dim3(256), 0, stream,
                       x, qkv_w, proj_w, xh, wqh, wph, Qh, Kh);
    hipLaunchKernelGGL(gemm_qkv, dim3(128, 9), dim3(256), 0, stream,
                       xh, wqh, qkv_b, Qh, Kh, VTh);
    hipLaunchKernelGGL(attn_mfma, dim3(64, 8, 4), dim3(256), 0, stream,
                       Qh, Kh, VTh, awsh);
    hipLaunchKernelGGL(gemm_proj, dim3(256, 3), dim3(128), 0, stream,
                       awsh, wph, proj_b, out);
}